// Round 3
// baseline (789.546 us; speedup 1.0000x reference)
//
#include <hip/hip_runtime.h>
#include <cstdint>
#include <cstddef>

// Problem dims (fixed by setup_inputs)
#define HDIM 1024
#define EEXP 16
#define BATCH 2048
#define MROWS (BATCH * EEXP)   // 32768
#define NHEADS 8
#define HEADD 128
#define KDIM 1024
#define LN_EPS 1e-5f

typedef __bf16 bf16x8_t __attribute__((ext_vector_type(8)));
typedef float f32x4_t __attribute__((ext_vector_type(4)));
typedef unsigned short u16x4_t __attribute__((ext_vector_type(4)));
typedef unsigned short u16x8_t __attribute__((ext_vector_type(8)));

__device__ __forceinline__ unsigned short f2bf(float f) {
    unsigned int u = __builtin_bit_cast(unsigned int, f);
    unsigned int r = (u + 0x7FFFu + ((u >> 16) & 1u)) >> 16;  // RNE
    return (unsigned short)r;
}
__device__ __forceinline__ float bf2f(unsigned short h) {
    unsigned int u = ((unsigned int)h) << 16;
    return __builtin_bit_cast(float, u);
}

// ---------------------------------------------------------------------------
// fp32 -> bf16 conversion for all 4 weight matrices in one launch.
// ---------------------------------------------------------------------------
__global__ __launch_bounds__(256) void k_conv4(
    const float* __restrict__ s0, const float* __restrict__ s1,
    const float* __restrict__ s2, const float* __restrict__ s3,
    unsigned short* __restrict__ d0, unsigned short* __restrict__ d1,
    unsigned short* __restrict__ d2, unsigned short* __restrict__ d3) {
    const int which = blockIdx.x >> 10;
    const int i = ((blockIdx.x & 1023) * 256 + threadIdx.x) * 4;
    const float* s = (which == 0) ? s0 : (which == 1) ? s1 : (which == 2) ? s2 : s3;
    unsigned short* d = (which == 0) ? d0 : (which == 1) ? d1 : (which == 2) ? d2 : d3;
    float4 v = *(const float4*)(s + i);
    u16x4_t o;
    o.x = f2bf(v.x); o.y = f2bf(v.y); o.z = f2bf(v.z); o.w = f2bf(v.w);
    *(u16x4_t*)(d + i) = o;
}

// ---------------------------------------------------------------------------
// comm (chain graph) + LayerNorm -> xn (bf16).  One block per row (b,e).
// ---------------------------------------------------------------------------
__global__ __launch_bounds__(256) void k_prep(const float* __restrict__ x,
                                              const float* __restrict__ lng,
                                              const float* __restrict__ lnb,
                                              unsigned short* __restrict__ xn) {
    const int m = blockIdx.x;
    const int e = m & (EEXP - 1);
    const int t = threadIdx.x;
    const int h = t * 4;
    const float* xr = x + (size_t)m * HDIM;

    float c0 = 0.f, c1 = 0.f, c2 = 0.f, c3 = 0.f;
    if (e > 0) {
        float4 v = *(const float4*)(xr - HDIM + h);
        c0 = 0.5f * v.x; c1 = 0.5f * v.y; c2 = 0.5f * v.z; c3 = 0.5f * v.w;
    }
    if (e < EEXP - 1) {
        float4 v = *(const float4*)(xr + HDIM + h);
        c0 += 0.5f * v.x; c1 += 0.5f * v.y; c2 += 0.5f * v.z; c3 += 0.5f * v.w;
    }
    float s  = c0 + c1 + c2 + c3;
    float ss = c0 * c0 + c1 * c1 + c2 * c2 + c3 * c3;
#pragma unroll
    for (int off = 32; off; off >>= 1) {
        s  += __shfl_xor(s, off, 64);
        ss += __shfl_xor(ss, off, 64);
    }
    __shared__ float red[8];
    const int wv = t >> 6;
    if ((t & 63) == 0) { red[wv] = s; red[4 + wv] = ss; }
    __syncthreads();
    s  = red[0] + red[1] + red[2] + red[3];
    ss = red[4] + red[5] + red[6] + red[7];
    const float mean = s * (1.0f / HDIM);
    const float var  = ss * (1.0f / HDIM) - mean * mean;
    const float rinv = rsqrtf(var + LN_EPS);

    float4 g = *(const float4*)(lng + h);
    float4 b = *(const float4*)(lnb + h);
    u16x4_t o;
    o.x = f2bf((c0 - mean) * rinv * g.x + b.x);
    o.y = f2bf((c1 - mean) * rinv * g.y + b.y);
    o.z = f2bf((c2 - mean) * rinv * g.z + b.z);
    o.w = f2bf((c3 - mean) * rinv * g.w + b.w);
    *(u16x4_t*)(xn + (size_t)m * HDIM + h) = o;
}

// ---------------------------------------------------------------------------
// bf16 GEMM, C[m,n] = sum_k A[m,k] * W[n,k]   (B^T layout).
// 128x128 tile, BK=64, 256 threads (4 waves, 2x2 of 64x64), mfma 16x16x32.
// - XCD supertile swizzle: xcd = blk&7 owns M-stripe [xcd*32, xcd*32+32),
//   walked in supertiles (8 mt x 12 nt for N=3072; 8 mt x 8 nt for N=1024)
//   so the concurrent per-XCD working set ~4-5 MB fits its private L2.
// - LDS 16B k-chunks XOR-swizzled by (row&7): ds_read_b128 2-way max (free).
// - MFMA operands swapped (mfma(b,a)): lane = one M-row, 4 consecutive
//   N-cols per acc group -> packed epilogue stores.
// ---------------------------------------------------------------------------
template <int N, bool IS_QKV>
__global__ __launch_bounds__(256) void k_gemm(
    const unsigned short* __restrict__ A,   // [M, K] bf16
    const unsigned short* __restrict__ Bw,  // [N, K] bf16
    const float* __restrict__ b0,           // bias (bq or bo)
    const float* __restrict__ b1,           // bk (QKV only)
    const float* __restrict__ b2,           // bv (QKV only)
    unsigned short* __restrict__ Cbf,       // QKV output
    float* __restrict__ Cf) {               // O output
    constexpr int K = KDIM;
    __shared__ unsigned short As[128 * 64];
    __shared__ unsigned short Bs[128 * 64];

    const int tid = threadIdx.x;
    // --- XCD supertile swizzle ---
    const int xcd = blockIdx.x & 7;
    const int g   = blockIdx.x >> 3;        // 0 .. grid/8-1
    int mt, nt;
    if constexpr (N == 3072) {
        const int st = g / 96, r = g % 96;  // 8 supertiles of 8x12
        mt = xcd * 32 + (st >> 1) * 8 + (r & 7);
        nt = (st & 1) * 12 + (r >> 3);
    } else {                                 // N == 1024
        const int st = g >> 6, r = g & 63;  // 4 supertiles of 8x8
        mt = xcd * 32 + st * 8 + (r & 7);
        nt = r >> 3;
    }
    const int m0 = mt * 128, n0 = nt * 128;

    const int lane = tid & 63, wave = tid >> 6;
    const int wm   = (wave >> 1) * 64, wn = (wave & 1) * 64;
    const int quad = lane >> 4, r16 = lane & 15;
    // staging: chunk c = q*256+tid -> row c>>3, phys col16 c&7; holds global
    // k-chunk (c&7)^(row&7).  LDS dest stays lane-contiguous (m104 caveat).
    const int srow = tid >> 3;               // row for q=0; +32 per q
    const int sgk  = ((tid & 7) ^ (srow & 7)) * 8;

    f32x4_t acc[4][4];
#pragma unroll
    for (int i = 0; i < 4; i++)
#pragma unroll
        for (int j = 0; j < 4; j++) acc[i][j] = f32x4_t{0.f, 0.f, 0.f, 0.f};

    f32x4_t bias4[4];
#pragma unroll
    for (int j = 0; j < 4; j++) {
        const int col0 = n0 + wn + j * 16 + quad * 4;
        const float* bp;
        if constexpr (IS_QKV) {
            bp = (col0 < 1024) ? (b0 + col0)
               : (col0 < 2048) ? (b1 + col0 - 1024)
                               : (b2 + col0 - 2048);
        } else {
            bp = b0 + col0;
        }
        bias4[j] = *(const f32x4_t*)bp;
    }

    // global row pointers for the 4 staging insts (q: row += 32)
    const unsigned short* Ag = A + (size_t)(m0 + srow) * K + sgk;
    const unsigned short* Bg = Bw + (size_t)(n0 + srow) * K + sgk;
    // ds_read swizzled chunk base for this lane (logical chunk l=h*4+quad)
    const int swz0 = ((0 * 4 + quad) ^ (r16 & 7)) * 8;
    const int swz1 = ((1 * 4 + quad) ^ (r16 & 7)) * 8;

    for (int k0 = 0; k0 < K; k0 += 64) {
        __syncthreads();  // previous iteration's LDS reads complete
#pragma unroll
        for (int q = 0; q < 4; q++) {
            __builtin_amdgcn_global_load_lds(
                (const __attribute__((address_space(1))) void*)(Ag + (size_t)(q * 32) * K + k0),
                (__attribute__((address_space(3))) void*)(As + q * 2048 + tid * 8), 16, 0, 0);
        }
#pragma unroll
        for (int q = 0; q < 4; q++) {
            __builtin_amdgcn_global_load_lds(
                (const __attribute__((address_space(1))) void*)(Bg + (size_t)(q * 32) * K + k0),
                (__attribute__((address_space(3))) void*)(Bs + q * 2048 + tid * 8), 16, 0, 0);
        }
        __syncthreads();  // tiles resident

#pragma unroll
        for (int h = 0; h < 2; h++) {
            const int swz = h ? swz1 : swz0;
            bf16x8_t a[4], b[4];
#pragma unroll
            for (int i = 0; i < 4; i++)
                a[i] = *(const bf16x8_t*)&As[(wm + i * 16 + r16) * 64 + swz];
#pragma unroll
            for (int j = 0; j < 4; j++)
                b[j] = *(const bf16x8_t*)&Bs[(wn + j * 16 + r16) * 64 + swz];
            // swapped operands: D[m = lane&15][n = quad*4 + reg]
#pragma unroll
            for (int i = 0; i < 4; i++)
#pragma unroll
                for (int j = 0; j < 4; j++)
                    acc[i][j] = __builtin_amdgcn_mfma_f32_16x16x32_bf16(b[j], a[i], acc[i][j], 0, 0, 0);
        }
    }

    // Epilogue: lane owns M-row (m0+wm+i*16+r16), 4 cols per j (packed).
#pragma unroll
    for (int i = 0; i < 4; i++) {
        const int grow = m0 + wm + i * 16 + r16;
#pragma unroll
        for (int j = 0; j < 4; j++) {
            const int col0 = n0 + wn + j * 16 + quad * 4;
            if constexpr (IS_QKV) {
                u16x4_t o;
                o.x = f2bf(acc[i][j][0] + bias4[j][0]);
                o.y = f2bf(acc[i][j][1] + bias4[j][1]);
                o.z = f2bf(acc[i][j][2] + bias4[j][2]);
                o.w = f2bf(acc[i][j][3] + bias4[j][3]);
                *(u16x4_t*)&Cbf[(size_t)grow * N + col0] = o;
            } else {
                f32x4_t o;
                o[0] = acc[i][j][0] + bias4[j][0];
                o[1] = acc[i][j][1] + bias4[j][1];
                o[2] = acc[i][j][2] + bias4[j][2];
                o[3] = acc[i][j][3] + bias4[j][3];
                *(f32x4_t*)&Cf[(size_t)grow * N + col0] = o;
            }
        }
    }
}

// ---------------------------------------------------------------------------
// Attention over E=16 per (b, head).  One block per (b*NHEADS + n).
// float4 LDS traffic throughout; packed u16x8 output stores.
// ---------------------------------------------------------------------------
__global__ __launch_bounds__(256) void k_attn(const unsigned short* __restrict__ qkv,
                                              unsigned short* __restrict__ att) {
    const int bidx = blockIdx.x;
    const int b = bidx >> 3, n = bidx & 7;
    __shared__ float qs[16][132], ks[16][132], vs[16][132];
    __shared__ float ps[16][17];
    const int t = threadIdx.x;

    {
        const int row = t >> 4, c0 = (t & 15) * 8;
        const size_t base = (size_t)(b * EEXP + row) * (3 * HDIM) + n * HEADD + c0;
        u16x8_t qv = *(const u16x8_t*)&qkv[base];
        u16x8_t kv = *(const u16x8_t*)&qkv[base + HDIM];
        u16x8_t vv = *(const u16x8_t*)&qkv[base + 2 * HDIM];
        f32x4_t q0, q1, k0, k1, v0, v1;
#pragma unroll
        for (int u = 0; u < 4; u++) {
            q0[u] = bf2f(qv[u]); q1[u] = bf2f(qv[u + 4]);
            k0[u] = bf2f(kv[u]); k1[u] = bf2f(kv[u + 4]);
            v0[u] = bf2f(vv[u]); v1[u] = bf2f(vv[u + 4]);
        }
        *(f32x4_t*)&qs[row][c0] = q0; *(f32x4_t*)&qs[row][c0 + 4] = q1;
        *(f32x4_t*)&ks[row][c0] = k0; *(f32x4_t*)&ks[row][c0 + 4] = k1;
        *(f32x4_t*)&vs[row][c0] = v0; *(f32x4_t*)&vs[row][c0 + 4] = v1;
    }
    __syncthreads();

    const int qe = t >> 4, ke = t & 15;
    float s = 0.f;
#pragma unroll
    for (int d = 0; d < HEADD; d += 4) {
        f32x4_t qv = *(const f32x4_t*)&qs[qe][d];
        f32x4_t kv = *(const f32x4_t*)&ks[ke][d];
        s += qv[0] * kv[0] + qv[1] * kv[1] + qv[2] * kv[2] + qv[3] * kv[3];
    }
    s *= 0.08838834764831845f;  // 1/sqrt(128)
    float mx = s;
#pragma unroll
    for (int off = 8; off; off >>= 1) mx = fmaxf(mx, __shfl_xor(mx, off, 16));
    const float ex = __expf(s - mx);
    float sum = ex;
#pragma unroll
    for (int off = 8; off; off >>= 1) sum += __shfl_xor(sum, off, 16);
    ps[qe][ke] = ex / sum;
    __syncthreads();

    // attended: thread owns (qe, 8 consecutive dims dd8)
    const int dd8 = (t & 15) * 8;
    float o[8] = {0.f, 0.f, 0.f, 0.f, 0.f, 0.f, 0.f, 0.f};
#pragma unroll
    for (int k2 = 0; k2 < EEXP; k2++) {
        const float p = ps[qe][k2];
        f32x4_t v0 = *(const f32x4_t*)&vs[k2][dd8];
        f32x4_t v1 = *(const f32x4_t*)&vs[k2][dd8 + 4];
        o[0] += p * v0[0]; o[1] += p * v0[1]; o[2] += p * v0[2]; o[3] += p * v0[3];
        o[4] += p * v1[0]; o[5] += p * v1[1]; o[6] += p * v1[2]; o[7] += p * v1[3];
    }
    u16x8_t ov;
#pragma unroll
    for (int u = 0; u < 8; u++) ov[u] = f2bf(o[u]);
    *(u16x8_t*)&att[(size_t)(b * EEXP + qe) * HDIM + n * HEADD + dd8] = ov;
}

// ---------------------------------------------------------------------------
// Residual + gate + blend.  One block per row.  In-place on d_out.
// ---------------------------------------------------------------------------
__global__ __launch_bounds__(256) void k_gate(const float* __restrict__ x,
                                              const float* __restrict__ wg,
                                              const float* __restrict__ bg,
                                              float* __restrict__ out) {
    const int m = blockIdx.x;
    const int e = m & (EEXP - 1);
    const int t = threadIdx.x;
    const int h = t * 4;
    const float* xr = x + (size_t)m * HDIM;
    float* orow = out + (size_t)m * HDIM;

    float4 xv = *(const float4*)(xr + h);
    float4 rv = *(const float4*)(orow + h);
    float c0 = 0.f, c1 = 0.f, c2 = 0.f, c3 = 0.f;
    if (e > 0) {
        float4 v = *(const float4*)(xr - HDIM + h);
        c0 = 0.5f * v.x; c1 = 0.5f * v.y; c2 = 0.5f * v.z; c3 = 0.5f * v.w;
    }
    if (e < EEXP - 1) {
        float4 v = *(const float4*)(xr + HDIM + h);
        c0 += 0.5f * v.x; c1 += 0.5f * v.y; c2 += 0.5f * v.z; c3 += 0.5f * v.w;
    }
    const float co0 = rv.x + c0, co1 = rv.y + c1, co2 = rv.z + c2, co3 = rv.w + c3;

    float4 w1 = *(const float4*)(wg + h);
    float4 w2 = *(const float4*)(wg + HDIM + h);
    float d = xv.x * w1.x + xv.y * w1.y + xv.z * w1.z + xv.w * w1.w +
              co0 * w2.x + co1 * w2.y + co2 * w2.z + co3 * w2.w;
#pragma unroll
    for (int off = 32; off; off >>= 1) d += __shfl_xor(d, off, 64);
    __shared__ float red[4];
    const int wv = t >> 6;
    if ((t & 63) == 0) red[wv] = d;
    __syncthreads();
    const float tot = red[0] + red[1] + red[2] + red[3] + bg[0];
    const float gate = 1.0f / (1.0f + __expf(-tot));

    float4 ov;
    ov.x = gate * co0 + (1.0f - gate) * xv.x;
    ov.y = gate * co1 + (1.0f - gate) * xv.y;
    ov.z = gate * co2 + (1.0f - gate) * xv.z;
    ov.w = gate * co3 + (1.0f - gate) * xv.w;
    *(float4*)(orow + h) = ov;
}

// ---------------------------------------------------------------------------
extern "C" void kernel_launch(void* const* d_in, const int* in_sizes, int n_in,
                              void* d_out, int out_size, void* d_ws, size_t ws_size,
                              hipStream_t stream) {
    const float* x   = (const float*)d_in[0];
    const float* lng = (const float*)d_in[1];
    const float* lnb = (const float*)d_in[2];
    const float* wq  = (const float*)d_in[3];
    const float* bq  = (const float*)d_in[4];
    const float* wk  = (const float*)d_in[5];
    const float* bk  = (const float*)d_in[6];
    const float* wv  = (const float*)d_in[7];
    const float* bv  = (const float*)d_in[8];
    const float* wo  = (const float*)d_in[9];
    const float* bo  = (const float*)d_in[10];
    const float* wg  = (const float*)d_in[11];
    const float* bg  = (const float*)d_in[12];
    float* out = (float*)d_out;

    // workspace layout (bf16 buffers), total ~344 MB
    unsigned short* wqkv = (unsigned short*)d_ws;                 // [3072,1024]
    unsigned short* wob  = wqkv + (size_t)3072 * 1024;            // [1024,1024]
    unsigned short* xn   = wob + (size_t)1024 * 1024;             // [M,1024]
    unsigned short* qkv  = xn + (size_t)MROWS * HDIM;             // [M,3072]
    unsigned short* att  = qkv + (size_t)MROWS * 3 * HDIM;        // [M,1024]

    const int WELTS = 1024 * 1024;
    k_conv4<<<4096, 256, 0, stream>>>(wq, wk, wv, wo,
                                      wqkv, wqkv + (size_t)WELTS,
                                      wqkv + (size_t)2 * WELTS, wob);

    k_prep<<<MROWS, 256, 0, stream>>>(x, lng, lnb, xn);

    k_gemm<3072, true><<<(MROWS / 128) * (3072 / 128), 256, 0, stream>>>(
        xn, wqkv, bq, bk, bv, qkv, nullptr);

    k_attn<<<BATCH * NHEADS, 256, 0, stream>>>(qkv, att);

    k_gemm<1024, false><<<(MROWS / 128) * (1024 / 128), 256, 0, stream>>>(
        att, wob, bo, nullptr, nullptr, nullptr, out);

    k_gate<<<MROWS, 256, 0, stream>>>(x, wg, bg, out);
}

// Round 4
// 707.420 us; speedup vs baseline: 1.1161x; 1.1161x over previous
//
#include <hip/hip_runtime.h>
#include <cstdint>
#include <cstddef>

// Problem dims (fixed by setup_inputs)
#define HDIM 1024
#define EEXP 16
#define BATCH 2048
#define MROWS (BATCH * EEXP)   // 32768
#define NHEADS 8
#define HEADD 128
#define KDIM 1024
#define LN_EPS 1e-5f

typedef __bf16 bf16x8_t __attribute__((ext_vector_type(8)));
typedef float f32x4_t __attribute__((ext_vector_type(4)));
typedef unsigned short u16x4_t __attribute__((ext_vector_type(4)));
typedef unsigned short u16x8_t __attribute__((ext_vector_type(8)));

__device__ __forceinline__ unsigned short f2bf(float f) {
    unsigned int u = __builtin_bit_cast(unsigned int, f);
    unsigned int r = (u + 0x7FFFu + ((u >> 16) & 1u)) >> 16;  // RNE
    return (unsigned short)r;
}
__device__ __forceinline__ float bf2f(unsigned short h) {
    unsigned int u = ((unsigned int)h) << 16;
    return __builtin_bit_cast(float, u);
}

// ---------------------------------------------------------------------------
// fp32 -> bf16 conversion for all 4 weight matrices in one launch.
// ---------------------------------------------------------------------------
__global__ __launch_bounds__(256) void k_conv4(
    const float* __restrict__ s0, const float* __restrict__ s1,
    const float* __restrict__ s2, const float* __restrict__ s3,
    unsigned short* __restrict__ d0, unsigned short* __restrict__ d1,
    unsigned short* __restrict__ d2, unsigned short* __restrict__ d3) {
    const int which = blockIdx.x >> 10;
    const int i = ((blockIdx.x & 1023) * 256 + threadIdx.x) * 4;
    const float* s = (which == 0) ? s0 : (which == 1) ? s1 : (which == 2) ? s2 : s3;
    unsigned short* d = (which == 0) ? d0 : (which == 1) ? d1 : (which == 2) ? d2 : d3;
    float4 v = *(const float4*)(s + i);
    u16x4_t o;
    o.x = f2bf(v.x); o.y = f2bf(v.y); o.z = f2bf(v.z); o.w = f2bf(v.w);
    *(u16x4_t*)(d + i) = o;
}

// ---------------------------------------------------------------------------
// comm (chain graph) + LayerNorm -> xn (bf16).  One block per row (b,e).
// ---------------------------------------------------------------------------
__global__ __launch_bounds__(256) void k_prep(const float* __restrict__ x,
                                              const float* __restrict__ lng,
                                              const float* __restrict__ lnb,
                                              unsigned short* __restrict__ xn) {
    const int m = blockIdx.x;
    const int e = m & (EEXP - 1);
    const int t = threadIdx.x;
    const int h = t * 4;
    const float* xr = x + (size_t)m * HDIM;

    float c0 = 0.f, c1 = 0.f, c2 = 0.f, c3 = 0.f;
    if (e > 0) {
        float4 v = *(const float4*)(xr - HDIM + h);
        c0 = 0.5f * v.x; c1 = 0.5f * v.y; c2 = 0.5f * v.z; c3 = 0.5f * v.w;
    }
    if (e < EEXP - 1) {
        float4 v = *(const float4*)(xr + HDIM + h);
        c0 += 0.5f * v.x; c1 += 0.5f * v.y; c2 += 0.5f * v.z; c3 += 0.5f * v.w;
    }
    float s  = c0 + c1 + c2 + c3;
    float ss = c0 * c0 + c1 * c1 + c2 * c2 + c3 * c3;
#pragma unroll
    for (int off = 32; off; off >>= 1) {
        s  += __shfl_xor(s, off, 64);
        ss += __shfl_xor(ss, off, 64);
    }
    __shared__ float red[8];
    const int wv = t >> 6;
    if ((t & 63) == 0) { red[wv] = s; red[4 + wv] = ss; }
    __syncthreads();
    s  = red[0] + red[1] + red[2] + red[3];
    ss = red[4] + red[5] + red[6] + red[7];
    const float mean = s * (1.0f / HDIM);
    const float var  = ss * (1.0f / HDIM) - mean * mean;
    const float rinv = rsqrtf(var + LN_EPS);

    float4 g = *(const float4*)(lng + h);
    float4 b = *(const float4*)(lnb + h);
    u16x4_t o;
    o.x = f2bf((c0 - mean) * rinv * g.x + b.x);
    o.y = f2bf((c1 - mean) * rinv * g.y + b.y);
    o.z = f2bf((c2 - mean) * rinv * g.z + b.z);
    o.w = f2bf((c3 - mean) * rinv * g.w + b.w);
    *(u16x4_t*)(xn + (size_t)m * HDIM + h) = o;
}

// ---------------------------------------------------------------------------
// bf16 GEMM, 256x256 tile, BK=64, 512 threads (8 waves as 2M x 4N), 8-phase
// schedule with counted vmcnt (T3+T4), st-swizzled LDS (T2), setprio (T5),
// XCD supertile swizzle (T1).  C[m,n] = sum_k A[m,k]*W[n,k] (B^T layout).
//
// LDS (128 KiB): regions r = buf*4 + {0:A-h0, 1:A-h1, 2:B-h0, 3:B-h1},
// each 128 rows x 64 k (16 KiB).  global_load_lds dest is LINEAR
// (base + tid*16B); the XOR k-chunk swizzle is applied on the GLOBAL source
// (chunk slot s of row r holds global chunk s^(r&7)); ds_read applies the
// same XOR -> 2-way max bank aliasing (free).
//
// Steady-state iteration i (tiles t0=2i in buf0, t1=2i+1 in buf1), one
// half-tile stage (2 x global_load_lds) per phase:
//   ph1: stage b1.A0(t1)   ph2: b1.A1(t1)   ph3: b0.B0(t2) ph4: b0.B1(t2)+VM4
//   ph5: b0.A0(t2)         ph6: b0.A1(t2)   ph7: b1.B0(t3) ph8: b1.B1(t3)+VM4
// At each VM4 there are 12 outstanding loads; vmcnt(4) lands the oldest 8
// (exactly what the next 4 phases read) and leaves 2 half-tiles in flight
// across the barrier.  Every region's stage is barrier-ordered after its
// last reader (B read only at ph1/ph5; A halves read through ph4/ph8).
// ---------------------------------------------------------------------------
template <int N, bool IS_QKV>
__global__ __launch_bounds__(512, 2) void k_gemm2(
    const unsigned short* __restrict__ A,   // [M, K] bf16
    const unsigned short* __restrict__ Bw,  // [N, K] bf16
    const float* __restrict__ b0,           // bias (bq or bo)
    const float* __restrict__ b1,           // bk (QKV only)
    const float* __restrict__ b2,           // bv (QKV only)
    unsigned short* __restrict__ Cbf,       // QKV output
    float* __restrict__ Cf) {               // O output
    constexpr int K = KDIM;
    __shared__ unsigned short S[65536];     // 128 KiB

    const int tid  = threadIdx.x;
    const int lane = tid & 63;
    const int wave = tid >> 6;
    const int quad = lane >> 4, r16 = lane & 15;
    const int wm2  = wave >> 2, wn4 = wave & 3;

    // --- XCD supertile swizzle: xcd owns 16 consecutive m-tiles ---
    const int xcd = blockIdx.x & 7;
    const int g   = blockIdx.x >> 3;
    int mt, nt;
    if constexpr (N == 3072) {               // 128 mt x 12 nt, grid 1536
        const int st = g / 48, r = g % 48;   // supertile 4mt x 12nt
        mt = xcd * 16 + st * 4 + (r & 3);
        nt = r >> 2;
    } else {                                 // N==1024: 128 mt x 4 nt, grid 512
        const int st = g >> 4, r = g & 15;   // supertile 4mt x 4nt
        mt = xcd * 16 + st * 4 + (r & 3);
        nt = r >> 2;
    }
    const int m0 = mt * 256, n0 = nt * 256;

    // staging lane constants: chunk c = q*512+tid -> row q*64+(tid>>3),
    // phys slot tid&7 holds global k-chunk (slot ^ (row&7)).
    const int srow0 = tid >> 3;
    const int gk = ((tid & 7) ^ (srow0 & 7)) * 8;
    const unsigned short* Ag = A  + (size_t)(m0 + srow0) * K + gk;
    const unsigned short* Bg = Bw + (size_t)(n0 + srow0) * K + gk;

    // ds_read lane constants (element offsets into S)
    const int swz0 = ((0 + quad) ^ (r16 & 7)) * 8;          // kk=0 chunk
    const int swz1 = ((4 + quad) ^ (r16 & 7)) * 8;          // kk=1 chunk
    const int aBase = wm2 * 8192 + r16 * 64;                // + f*1024 + swz
    const int bBase = (2 + (wn4 >> 1)) * 8192 + (wn4 & 1) * 4096 + r16 * 64;

    f32x4_t acc[8][4];
#pragma unroll
    for (int f = 0; f < 8; ++f)
#pragma unroll
        for (int j = 0; j < 4; ++j) acc[f][j] = f32x4_t{0.f, 0.f, 0.f, 0.f};

    bf16x8_t bfr[4][2];   // B fragments, held across the 4 phases of a K-tile

#define STG(reg, srcb, rowoff, kk0)                                                          \
    do {                                                                                     \
        __builtin_amdgcn_global_load_lds(                                                    \
            (const __attribute__((address_space(1))) void*)((srcb) + (size_t)(rowoff) * K + (kk0)),       \
            (__attribute__((address_space(3))) void*)(S + (reg) * 8192 + tid * 8), 16, 0, 0);             \
        __builtin_amdgcn_global_load_lds(                                                    \
            (const __attribute__((address_space(1))) void*)((srcb) + (size_t)((rowoff) + 64) * K + (kk0)),\
            (__attribute__((address_space(3))) void*)(S + (reg) * 8192 + 4096 + tid * 8), 16, 0, 0);      \
    } while (0)

#define DSRD_B(buf)                                                                          \
    do {                                                                                     \
        _Pragma("unroll") for (int j = 0; j < 4; ++j) {                                      \
            bfr[j][0] = *(const bf16x8_t*)&S[(buf) * 32768 + bBase + j * 1024 + swz0];       \
            bfr[j][1] = *(const bf16x8_t*)&S[(buf) * 32768 + bBase + j * 1024 + swz1];       \
        }                                                                                    \
    } while (0)

#define VM4 asm volatile("s_waitcnt vmcnt(4)" ::: "memory")
#define VM0 asm volatile("s_waitcnt vmcnt(0)" ::: "memory")
#define NOSTG ((void)0)
#define NOWAIT ((void)0)

#define PHASE(buf, ph, STAGE_STMT, WAIT_STMT)                                                \
    do {                                                                                     \
        bf16x8_t afr[2][2];                                                                  \
        _Pragma("unroll") for (int s2 = 0; s2 < 2; ++s2) {                                   \
            afr[s2][0] = *(const bf16x8_t*)&S[(buf) * 32768 + aBase + ((ph) * 2 + s2) * 1024 + swz0]; \
            afr[s2][1] = *(const bf16x8_t*)&S[(buf) * 32768 + aBase + ((ph) * 2 + s2) * 1024 + swz1]; \
        }                                                                                    \
        STAGE_STMT;                                                                          \
        WAIT_STMT;                                                                           \
        __builtin_amdgcn_s_barrier();                                                        \
        asm volatile("s_waitcnt lgkmcnt(0)" ::: "memory");                                   \
        __builtin_amdgcn_s_setprio(1);                                                       \
        _Pragma("unroll") for (int s2 = 0; s2 < 2; ++s2)                                     \
            _Pragma("unroll") for (int j = 0; j < 4; ++j) {                                  \
                acc[(ph) * 2 + s2][j] = __builtin_amdgcn_mfma_f32_16x16x32_bf16(             \
                    bfr[j][0], afr[s2][0], acc[(ph) * 2 + s2][j], 0, 0, 0);                  \
                acc[(ph) * 2 + s2][j] = __builtin_amdgcn_mfma_f32_16x16x32_bf16(             \
                    bfr[j][1], afr[s2][1], acc[(ph) * 2 + s2][j], 0, 0, 0);                  \
            }                                                                                \
        __builtin_amdgcn_s_setprio(0);                                                       \
        __builtin_amdgcn_s_barrier();                                                        \
    } while (0)

    // ---- prologue: stage t0 fully (buf0) + t1's B halves (buf1) ----
    STG(0, Ag, 0,   0);     // buf0.A0  t0
    STG(1, Ag, 128, 0);     // buf0.A1  t0
    STG(2, Bg, 0,   0);     // buf0.B0  t0
    STG(3, Bg, 128, 0);     // buf0.B1  t0
    STG(6, Bg, 0,   64);    // buf1.B0  t1
    STG(7, Bg, 128, 64);    // buf1.B1  t1
    VM4;                    // buf0's 8 loads landed; b1.B stays in flight
    __builtin_amdgcn_s_barrier();

#pragma unroll 1
    for (int i = 0; i < 7; ++i) {
        const int kA1 = (2 * i + 1) * 64;   // buf1.A target (tile 2i+1)
        const int kN2 = (2 * i + 2) * 64;   // buf0 target   (tile 2i+2)
        const int kN3 = (2 * i + 3) * 64;   // buf1.B target (tile 2i+3)
        DSRD_B(0);
        PHASE(0, 0, STG(4, Ag, 0,   kA1), NOWAIT);
        PHASE(0, 1, STG(5, Ag, 128, kA1), NOWAIT);
        PHASE(0, 2, STG(2, Bg, 0,   kN2), NOWAIT);
        PHASE(0, 3, STG(3, Bg, 128, kN2), VM4);
        DSRD_B(1);
        PHASE(1, 0, STG(0, Ag, 0,   kN2), NOWAIT);
        PHASE(1, 1, STG(1, Ag, 128, kN2), NOWAIT);
        PHASE(1, 2, STG(6, Bg, 0,   kN3), NOWAIT);
        PHASE(1, 3, STG(7, Bg, 128, kN3), VM4);
    }
    // ---- epilogue iteration: tiles 14 (buf0), 15 (buf1) ----
    {
        DSRD_B(0);
        PHASE(0, 0, STG(4, Ag, 0,   960), NOWAIT);
        PHASE(0, 1, STG(5, Ag, 128, 960), NOWAIT);
        PHASE(0, 2, NOSTG, NOWAIT);
        PHASE(0, 3, NOSTG, VM0);
        DSRD_B(1);
        PHASE(1, 0, NOSTG, NOWAIT);
        PHASE(1, 1, NOSTG, NOWAIT);
        PHASE(1, 2, NOSTG, NOWAIT);
        PHASE(1, 3, NOSTG, NOWAIT);
    }

    // ---- C epilogue (bias loaded here so the loop's vmcnt counts stay exact)
    f32x4_t bias4[4];
#pragma unroll
    for (int j = 0; j < 4; ++j) {
        const int gcol = n0 + wn4 * 64 + j * 16 + quad * 4;
        const float* bp;
        if constexpr (IS_QKV) {
            bp = (gcol < 1024) ? (b0 + gcol)
               : (gcol < 2048) ? (b1 + gcol - 1024)
                               : (b2 + gcol - 2048);
        } else {
            bp = b0 + gcol;
        }
        bias4[j] = *(const f32x4_t*)bp;
    }

#pragma unroll
    for (int f = 0; f < 8; ++f) {
        const int grow = m0 + wm2 * 128 + f * 16 + r16;
#pragma unroll
        for (int j = 0; j < 4; ++j) {
            const int gcol = n0 + wn4 * 64 + j * 16 + quad * 4;
            if constexpr (IS_QKV) {
                u16x4_t o;
                o.x = f2bf(acc[f][j][0] + bias4[j][0]);
                o.y = f2bf(acc[f][j][1] + bias4[j][1]);
                o.z = f2bf(acc[f][j][2] + bias4[j][2]);
                o.w = f2bf(acc[f][j][3] + bias4[j][3]);
                *(u16x4_t*)&Cbf[(size_t)grow * N + gcol] = o;
            } else {
                f32x4_t o;
                o[0] = acc[f][j][0] + bias4[j][0];
                o[1] = acc[f][j][1] + bias4[j][1];
                o[2] = acc[f][j][2] + bias4[j][2];
                o[3] = acc[f][j][3] + bias4[j][3];
                *(f32x4_t*)&Cf[(size_t)grow * N + gcol] = o;
            }
        }
    }
#undef STG
#undef DSRD_B
#undef PHASE
#undef VM4
#undef VM0
#undef NOSTG
#undef NOWAIT
}

// ---------------------------------------------------------------------------
// Attention over E=16 per (b, head).  One block per (b*NHEADS + n).
// ---------------------------------------------------------------------------
__global__ __launch_bounds__(256) void k_attn(const unsigned short* __restrict__ qkv,
                                              unsigned short* __restrict__ att) {
    const int bidx = blockIdx.x;
    const int b = bidx >> 3, n = bidx & 7;
    __shared__ float qs[16][132], ks[16][132], vs[16][132];
    __shared__ float ps[16][17];
    const int t = threadIdx.x;

    {
        const int row = t >> 4, c0 = (t & 15) * 8;
        const size_t base = (size_t)(b * EEXP + row) * (3 * HDIM) + n * HEADD + c0;
        u16x8_t qv = *(const u16x8_t*)&qkv[base];
        u16x8_t kv = *(const u16x8_t*)&qkv[base + HDIM];
        u16x8_t vv = *(const u16x8_t*)&qkv[base + 2 * HDIM];
        f32x4_t q0, q1, k0, k1, v0, v1;
#pragma unroll
        for (int u = 0; u < 4; u++) {
            q0[u] = bf2f(qv[u]); q1[u] = bf2f(qv[u + 4]);
            k0[u] = bf2f(kv[u]); k1[u] = bf2f(kv[u + 4]);
            v0[u] = bf2f(vv[u]); v1[u] = bf2f(vv[u + 4]);
        }
        *(f32x4_t*)&qs[row][c0] = q0; *(f32x4_t*)&qs[row][c0 + 4] = q1;
        *(f32x4_t*)&ks[row][c0] = k0; *(f32x4_t*)&ks[row][c0 + 4] = k1;
        *(f32x4_t*)&vs[row][c0] = v0; *(f32x4_t*)&vs[row][c0 + 4] = v1;
    }
    __syncthreads();

    const int qe = t >> 4, ke = t & 15;
    float s = 0.f;
#pragma unroll
    for (int d = 0; d < HEADD; d += 4) {
        f32x4_t qv = *(const f32x4_t*)&qs[qe][d];
        f32x4_t kv = *(const f32x4_t*)&ks[ke][d];
        s += qv[0] * kv[0] + qv[1] * kv[1] + qv[2] * kv[2] + qv[3] * kv[3];
    }
    s *= 0.08838834764831845f;  // 1/sqrt(128)
    float mx = s;
#pragma unroll
    for (int off = 8; off; off >>= 1) mx = fmaxf(mx, __shfl_xor(mx, off, 16));
    const float ex = __expf(s - mx);
    float sum = ex;
#pragma unroll
    for (int off = 8; off; off >>= 1) sum += __shfl_xor(sum, off, 16);
    ps[qe][ke] = ex / sum;
    __syncthreads();

    const int dd8 = (t & 15) * 8;
    float o[8] = {0.f, 0.f, 0.f, 0.f, 0.f, 0.f, 0.f, 0.f};
#pragma unroll
    for (int k2 = 0; k2 < EEXP; k2++) {
        const float p = ps[qe][k2];
        f32x4_t v0 = *(const f32x4_t*)&vs[k2][dd8];
        f32x4_t v1 = *(const f32x4_t*)&vs[k2][dd8 + 4];
        o[0] += p * v0[0]; o[1] += p * v0[1]; o[2] += p * v0[2]; o[3] += p * v0[3];
        o[4] += p * v1[0]; o[5] += p * v1[1]; o[6] += p * v1[2]; o[7] += p * v1[3];
    }
    u16x8_t ov;
#pragma unroll
    for (int u = 0; u < 8; u++) ov[u] = f2bf(o[u]);
    *(u16x8_t*)&att[(size_t)(b * EEXP + qe) * HDIM + n * HEADD + dd8] = ov;
}

// ---------------------------------------------------------------------------
// Residual + gate + blend.  One block per row.  In-place on d_out.
// ---------------------------------------------------------------------------
__global__ __launch_bounds__(256) void k_gate(const float* __restrict__ x,
                                              const float* __restrict__ wg,
                                              const float* __restrict__ bg,
                                              float* __restrict__ out) {
    const int m = blockIdx.x;
    const int e = m & (EEXP - 1);
    const int t = threadIdx.x;
    const int h = t * 4;
    const float* xr = x + (size_t)m * HDIM;
    float* orow = out + (size_t)m * HDIM;

    float4 xv = *(const float4*)(xr + h);
    float4 rv = *(const float4*)(orow + h);
    float c0 = 0.f, c1 = 0.f, c2 = 0.f, c3 = 0.f;
    if (e > 0) {
        float4 v = *(const float4*)(xr - HDIM + h);
        c0 = 0.5f * v.x; c1 = 0.5f * v.y; c2 = 0.5f * v.z; c3 = 0.5f * v.w;
    }
    if (e < EEXP - 1) {
        float4 v = *(const float4*)(xr + HDIM + h);
        c0 += 0.5f * v.x; c1 += 0.5f * v.y; c2 += 0.5f * v.z; c3 += 0.5f * v.w;
    }
    const float co0 = rv.x + c0, co1 = rv.y + c1, co2 = rv.z + c2, co3 = rv.w + c3;

    float4 w1 = *(const float4*)(wg + h);
    float4 w2 = *(const float4*)(wg + HDIM + h);
    float d = xv.x * w1.x + xv.y * w1.y + xv.z * w1.z + xv.w * w1.w +
              co0 * w2.x + co1 * w2.y + co2 * w2.z + co3 * w2.w;
#pragma unroll
    for (int off = 32; off; off >>= 1) d += __shfl_xor(d, off, 64);
    __shared__ float red[4];
    const int wv = t >> 6;
    if ((t & 63) == 0) red[wv] = d;
    __syncthreads();
    const float tot = red[0] + red[1] + red[2] + red[3] + bg[0];
    const float gate = 1.0f / (1.0f + __expf(-tot));

    float4 ov;
    ov.x = gate * co0 + (1.0f - gate) * xv.x;
    ov.y = gate * co1 + (1.0f - gate) * xv.y;
    ov.z = gate * co2 + (1.0f - gate) * xv.z;
    ov.w = gate * co3 + (1.0f - gate) * xv.w;
    *(float4*)(orow + h) = ov;
}

// ---------------------------------------------------------------------------
extern "C" void kernel_launch(void* const* d_in, const int* in_sizes, int n_in,
                              void* d_out, int out_size, void* d_ws, size_t ws_size,
                              hipStream_t stream) {
    const float* x   = (const float*)d_in[0];
    const float* lng = (const float*)d_in[1];
    const float* lnb = (const float*)d_in[2];
    const float* wq  = (const float*)d_in[3];
    const float* bq  = (const float*)d_in[4];
    const float* wk  = (const float*)d_in[5];
    const float* bk  = (const float*)d_in[6];
    const float* wv  = (const float*)d_in[7];
    const float* bv  = (const float*)d_in[8];
    const float* wo  = (const float*)d_in[9];
    const float* bo  = (const float*)d_in[10];
    const float* wg  = (const float*)d_in[11];
    const float* bg  = (const float*)d_in[12];
    float* out = (float*)d_out;

    // workspace layout (bf16 buffers), total ~344 MB
    unsigned short* wqkv = (unsigned short*)d_ws;                 // [3072,1024]
    unsigned short* wob  = wqkv + (size_t)3072 * 1024;            // [1024,1024]
    unsigned short* xn   = wob + (size_t)1024 * 1024;             // [M,1024]
    unsigned short* qkv  = xn + (size_t)MROWS * HDIM;             // [M,3072]
    unsigned short* att  = qkv + (size_t)MROWS * 3 * HDIM;        // [M,1024]

    const int WELTS = 1024 * 1024;
    k_conv4<<<4096, 256, 0, stream>>>(wq, wk, wv, wo,
                                      wqkv, wqkv + (size_t)WELTS,
                                      wqkv + (size_t)2 * WELTS, wob);

    k_prep<<<MROWS, 256, 0, stream>>>(x, lng, lnb, xn);

    k_gemm2<3072, true><<<(MROWS / 256) * (3072 / 256), 512, 0, stream>>>(
        xn, wqkv, bq, bk, bv, qkv, nullptr);

    k_attn<<<BATCH * NHEADS, 256, 0, stream>>>(qkv, att);

    k_gemm2<1024, false><<<(MROWS / 256) * (1024 / 256), 512, 0, stream>>>(
        att, wob, bo, nullptr, nullptr, nullptr, out);

    k_gate<<<MROWS, 256, 0, stream>>>(x, wg, bg, out);
}